// Round 1
// baseline (895.691 us; speedup 1.0000x reference)
//
#include <hip/hip_runtime.h>
#include <hip/hip_bf16.h>
#include <math.h>

#define GENES 1000

// ---------------- CSR build ----------------

__global__ void k_deg(const int* __restrict__ ei, int* __restrict__ deg, int E) {
  int e = blockIdx.x * blockDim.x + threadIdx.x;
  if (e < E) atomicAdd(&deg[ei[E + e]], 1);
}

__global__ void k_scan(const int* __restrict__ deg, int* __restrict__ ptr, int n) {
  // single block, 1024 threads, exclusive scan -> ptr[0..n]
  __shared__ int wsum[16];
  __shared__ int carry_s;
  int t = threadIdx.x;
  int lane = t & 63, w = t >> 6;
  if (t == 0) { carry_s = 0; ptr[0] = 0; }
  __syncthreads();
  for (int base = 0; base < n; base += 1024) {
    int i = base + t;
    int x = (i < n) ? deg[i] : 0;
    #pragma unroll
    for (int d = 1; d < 64; d <<= 1) {
      int y = __shfl_up(x, d);
      if (lane >= d) x += y;
    }
    if (lane == 63) wsum[w] = x;
    __syncthreads();
    if (t == 0) {
      int s = 0;
      #pragma unroll
      for (int k = 0; k < 16; ++k) { s += wsum[k]; wsum[k] = s; }
    }
    __syncthreads();
    int woff = (w == 0) ? 0 : wsum[w - 1];
    int incl = carry_s + woff + x;
    if (i < n) ptr[i + 1] = incl;
    __syncthreads();
    if (t == 1023) carry_s = incl;
    __syncthreads();
  }
}

__global__ void k_scatter(const int* __restrict__ ei, const int* __restrict__ ptr,
                          int* __restrict__ cur, int* __restrict__ srcs, int E) {
  int e = blockIdx.x * blockDim.x + threadIdx.x;
  if (e >= E) return;
  int d = ei[E + e];
  int pos = ptr[d] + atomicAdd(&cur[d], 1);
  srcs[pos] = ei[e];
}

// ---------------- dense GEMM (fp32, LDS-staged) ----------------

template<int NC>
__global__ void k_gemm(const float* __restrict__ A, const float* __restrict__ W,
                       float* __restrict__ out, int M, int K) {
  constexpr int TR = 32;            // tile rows
  constexpr int RG = 256 / NC;      // row groups
  constexpr int RPT = TR / RG;      // rows per thread
  __shared__ float xs[TR][8];
  int t = threadIdx.x;
  int col = t % NC, rg = t / NC;
  long row0 = (long)blockIdx.x * TR;
  float acc[RPT];
  #pragma unroll
  for (int r = 0; r < RPT; ++r) acc[r] = 0.f;
  int lr = t >> 3, lc = t & 7;
  for (int k0 = 0; k0 < K; k0 += 8) {
    long grow = row0 + lr;
    xs[lr][lc] = (grow < M) ? A[grow * K + k0 + lc] : 0.f;
    __syncthreads();
    #pragma unroll
    for (int kk = 0; kk < 8; ++kk) {
      float w = W[(long)(k0 + kk) * NC + col];
      #pragma unroll
      for (int r = 0; r < RPT; ++r)
        acc[r] += xs[rg * RPT + r][kk] * w;
    }
    __syncthreads();
  }
  #pragma unroll
  for (int r = 0; r < RPT; ++r) {
    long row = row0 + rg * RPT + r;
    if (row < M) out[row * NC + col] = acc[r];
  }
}

// ---------------- attention coefficients ----------------

__global__ void k_al(const float* __restrict__ h, const float* __restrict__ a_s,
                     const float* __restrict__ a_d, float* __restrict__ als,
                     float* __restrict__ ald, int n, int H, int C) {
  int t = blockIdx.x * blockDim.x + threadIdx.x;
  if (t >= n * H) return;
  int hd = t % H;
  const float* hp = h + (long)t * C;
  float s1 = 0.f, s2 = 0.f;
  for (int c = 0; c < C; ++c) {
    float v = hp[c];
    s1 += v * a_s[hd * C + c];
    s2 += v * a_d[hd * C + c];
  }
  als[t] = s1; ald[t] = s2;
}

// ---------------- per-dst aggregation, H=8, C=16 (128 ch) ----------------

__global__ void k_agg128(const float* __restrict__ h, const float* __restrict__ als,
                         const float* __restrict__ ald, const int* __restrict__ ptr,
                         const int* __restrict__ srcs, const float* __restrict__ bias,
                         float* __restrict__ out, int n, int do_elu) {
  int wid = (int)(((long)blockIdx.x * blockDim.x + threadIdx.x) >> 6);
  if (wid >= n) return;
  int lane = threadIdx.x & 63;
  int p0 = ptr[wid], deg = ptr[wid + 1] - p0;
  // pass 1: per-head max of leaky_relu logits (head = lane&7, 8 edge lanes)
  int hA = lane & 7;
  float aldA = ald[wid * 8 + hA];
  float mx = -1e30f;
  for (int j = (lane >> 3); j < deg; j += 8) {
    float l = als[srcs[p0 + j] * 8 + hA] + aldA;
    l = l > 0.f ? l : 0.2f * l;
    mx = fmaxf(mx, l);
  }
  #pragma unroll
  for (int d = 8; d < 64; d <<= 1) mx = fmaxf(mx, __shfl_xor(mx, d));
  // pass 2: lane owns channels 2l,2l+1 -> head = lane>>3
  int hB = lane >> 3;
  float m = __shfl(mx, hB);
  float aldB = ald[wid * 8 + hB];
  int c0 = 2 * lane;
  float acc0 = 0.f, acc1 = 0.f, dsum = 0.f;
  for (int j = 0; j < deg; ++j) {
    int s = srcs[p0 + j];
    float l = als[s * 8 + hB] + aldB;
    l = l > 0.f ? l : 0.2f * l;
    float e = __expf(l - m);
    dsum += e;
    const float2 hv = *(const float2*)(h + (long)s * 128 + c0);
    acc0 += e * hv.x;
    acc1 += e * hv.y;
  }
  float inv = 1.f / (dsum + 1e-16f);
  float o0 = acc0 * inv + bias[c0];
  float o1 = acc1 * inv + bias[c0 + 1];
  if (do_elu) {
    o0 = o0 > 0.f ? o0 : (__expf(o0) - 1.f);
    o1 = o1 > 0.f ? o1 : (__expf(o1) - 1.f);
  }
  *(float2*)(out + (long)wid * 128 + c0) = make_float2(o0, o1);
}

// ---------------- per-dst aggregation, H=1, C=16 ----------------

__global__ void k_agg16(const float* __restrict__ h, const float* __restrict__ als,
                        const float* __restrict__ ald, const int* __restrict__ ptr,
                        const int* __restrict__ srcs, const float* __restrict__ bias,
                        float* __restrict__ out, int n) {
  int wid = (int)(((long)blockIdx.x * blockDim.x + threadIdx.x) >> 6);
  if (wid >= n) return;
  int lane = threadIdx.x & 63;
  int p0 = ptr[wid], deg = ptr[wid + 1] - p0;
  float aldv = ald[wid];
  float mx = -1e30f;
  for (int j = lane; j < deg; j += 64) {
    float l = als[srcs[p0 + j]] + aldv;
    l = l > 0.f ? l : 0.2f * l;
    mx = fmaxf(mx, l);
  }
  #pragma unroll
  for (int d = 1; d < 64; d <<= 1) mx = fmaxf(mx, __shfl_xor(mx, d));
  // 4 groups of 16 lanes; group g handles edges g, g+4, ...
  int g = lane >> 4, c = lane & 15;
  float acc = 0.f, dsum = 0.f;
  for (int j = g; j < deg; j += 4) {
    int s = srcs[p0 + j];
    float l = als[s] + aldv;
    l = l > 0.f ? l : 0.2f * l;
    float e = __expf(l - mx);
    dsum += e;
    acc += e * h[(long)s * 16 + c];
  }
  #pragma unroll
  for (int d = 16; d < 64; d <<= 1) {
    acc += __shfl_xor(acc, d);
    dsum += __shfl_xor(dsum, d);
  }
  if (lane < 16)
    out[(long)wid * 16 + lane] = acc / (dsum + 1e-16f) + bias[lane];
}

// ---------------- launch ----------------

extern "C" void kernel_launch(void* const* d_in, const int* in_sizes, int n_in,
                              void* d_out, int out_size, void* d_ws, size_t ws_size,
                              hipStream_t stream) {
  const float* x  = (const float*)d_in[0];
  const int*   ei = (const int*)d_in[1];
  const float* W0 = (const float*)d_in[2];
  const float* as0= (const float*)d_in[3];
  const float* ad0= (const float*)d_in[4];
  const float* b0 = (const float*)d_in[5];
  const float* W1 = (const float*)d_in[6];
  const float* as1= (const float*)d_in[7];
  const float* ad1= (const float*)d_in[8];
  const float* b1 = (const float*)d_in[9];
  const float* W2 = (const float*)d_in[10];
  const float* as2= (const float*)d_in[11];
  const float* ad2= (const float*)d_in[12];
  const float* b2 = (const float*)d_in[13];
  float* out = (float*)d_out;

  int E = in_sizes[1] / 2;
  int n = in_sizes[0] / GENES;

  char* ws = (char*)d_ws;
  size_t off = 0;
  auto alloc = [&](size_t bytes) {
    void* p = ws + off;
    off = (off + bytes + 255) & ~(size_t)255;
    return p;
  };
  int* ptr   = (int*)alloc((size_t)(n + 1) * sizeof(int));
  int* cur   = (int*)alloc((size_t)n * sizeof(int));
  int* srcs  = (int*)alloc((size_t)E * sizeof(int));
  float* A   = (float*)alloc((size_t)n * 128 * sizeof(float));
  float* B   = (float*)alloc((size_t)n * 128 * sizeof(float));
  float* als = (float*)alloc((size_t)n * 8 * sizeof(float));
  float* ald = (float*)alloc((size_t)n * 8 * sizeof(float));

  int eb = (E + 255) / 256;
  hipMemsetAsync(cur, 0, (size_t)n * sizeof(int), stream);
  k_deg<<<eb, 256, 0, stream>>>(ei, cur, E);
  k_scan<<<1, 1024, 0, stream>>>(cur, ptr, n);
  hipMemsetAsync(cur, 0, (size_t)n * sizeof(int), stream);
  k_scatter<<<eb, 256, 0, stream>>>(ei, ptr, cur, srcs, E);

  int gb   = (n + 31) / 32;
  int aggb = (int)(((long)n * 64 + 255) / 256);
  int alb  = (n * 8 + 255) / 256;
  int alb1 = (n + 255) / 256;

  // layer 0: x @ W0 -> A, attention, aggregate -> B (ELU)
  k_gemm<128><<<gb, 256, 0, stream>>>(x, W0, A, n, GENES);
  k_al<<<alb, 256, 0, stream>>>(A, as0, ad0, als, ald, n, 8, 16);
  k_agg128<<<aggb, 256, 0, stream>>>(A, als, ald, ptr, srcs, b0, B, n, 1);

  // layer 1: B @ W1 -> A, aggregate -> B (ELU)
  k_gemm<128><<<gb, 256, 0, stream>>>(B, W1, A, n, 128);
  k_al<<<alb, 256, 0, stream>>>(A, as1, ad1, als, ald, n, 8, 16);
  k_agg128<<<aggb, 256, 0, stream>>>(A, als, ald, ptr, srcs, b1, B, n, 1);

  // layer 2: B @ W2 -> A[n*16], aggregate -> out (no ELU)
  k_gemm<16><<<gb, 256, 0, stream>>>(B, W2, A, n, 128);
  k_al<<<alb1, 256, 0, stream>>>(A, as2, ad2, als, ald, n, 1, 16);
  k_agg16<<<aggb, 256, 0, stream>>>(A, als, ald, ptr, srcs, b2, out, n);
}

// Round 2
// 538.385 us; speedup vs baseline: 1.6637x; 1.6637x over previous
//
#include <hip/hip_runtime.h>
#include <hip/hip_bf16.h>
#include <math.h>

#define GENES 1000

typedef __attribute__((ext_vector_type(8))) short short8;
typedef __attribute__((ext_vector_type(4))) float f32x4;

__device__ inline unsigned short f2bf(float f) {
  unsigned int u = __float_as_uint(f);
  u += 0x7fff + ((u >> 16) & 1);
  return (unsigned short)(u >> 16);
}
__device__ inline float bf2f(unsigned short s) {
  return __uint_as_float(((unsigned int)s) << 16);
}

// ---------------- CSR build ----------------

__global__ void k_deg(const int* __restrict__ ei, int* __restrict__ deg, int E) {
  int e = blockIdx.x * blockDim.x + threadIdx.x;
  if (e < E) atomicAdd(&deg[ei[E + e]], 1);
}

__global__ void k_scan(const int* __restrict__ deg, int* __restrict__ ptr, int n) {
  __shared__ int wsum[16];
  __shared__ int carry_s;
  int t = threadIdx.x;
  int lane = t & 63, w = t >> 6;
  if (t == 0) { carry_s = 0; ptr[0] = 0; }
  __syncthreads();
  for (int base = 0; base < n; base += 1024) {
    int i = base + t;
    int x = (i < n) ? deg[i] : 0;
    #pragma unroll
    for (int d = 1; d < 64; d <<= 1) {
      int y = __shfl_up(x, d);
      if (lane >= d) x += y;
    }
    if (lane == 63) wsum[w] = x;
    __syncthreads();
    if (t == 0) {
      int s = 0;
      #pragma unroll
      for (int k = 0; k < 16; ++k) { s += wsum[k]; wsum[k] = s; }
    }
    __syncthreads();
    int woff = (w == 0) ? 0 : wsum[w - 1];
    int incl = carry_s + woff + x;
    if (i < n) ptr[i + 1] = incl;
    __syncthreads();
    if (t == 1023) carry_s = incl;
    __syncthreads();
  }
}

__global__ void k_scatter(const int* __restrict__ ei, const int* __restrict__ ptr,
                          int* __restrict__ cur, int* __restrict__ srcs, int E) {
  int e = blockIdx.x * blockDim.x + threadIdx.x;
  if (e >= E) return;
  int d = ei[E + e];
  int pos = ptr[d] + atomicAdd(&cur[d], 1);
  srcs[pos] = ei[e];
}

// ---------------- W split/transpose: W[K x 128] -> Wt_hi/Wt_lo [128][1024] ----------------

__global__ void k_wsplit(const float* __restrict__ W, unsigned short* __restrict__ Wh,
                         unsigned short* __restrict__ Wl, int K) {
  int t = blockIdx.x * blockDim.x + threadIdx.x;  // over 128*1024
  if (t >= 128 * 1024) return;
  int col = t >> 10, k = t & 1023;
  float v = (k < K) ? W[(long)k * 128 + col] : 0.f;
  unsigned short hi = f2bf(v);
  float lo = v - bf2f(hi);
  Wh[t] = hi;
  Wl[t] = f2bf(lo);
}

// ---------------- MFMA split-bf16 GEMM: A[MxK] fp32 @ W[Kx128] -> out[Mx128] fp32 ----------

__global__ __launch_bounds__(256) void k_mgemm(
    const float* __restrict__ A, const unsigned short* __restrict__ Wh,
    const unsigned short* __restrict__ Wl, float* __restrict__ out, int M, int K) {
  // BM=64, BN=128, BK=32; 4 waves, wave w owns rows 0..63 x cols [w*32, w*32+32)
  __shared__ unsigned short As_h[64 * 40];   // stride 40 shorts = 80B (2-way banks)
  __shared__ unsigned short As_l[64 * 40];
  __shared__ unsigned short Bs_h[128 * 40];
  __shared__ unsigned short Bs_l[128 * 40];
  int t = threadIdx.x;
  int lane = t & 63, w = t >> 6;
  long row0 = (long)blockIdx.x * 64;

  f32x4 acc[4][2];
  #pragma unroll
  for (int m = 0; m < 4; ++m)
    #pragma unroll
    for (int n = 0; n < 2; ++n)
      acc[m][n] = (f32x4){0.f, 0.f, 0.f, 0.f};

  int sr = t >> 2, sq = t & 3;   // A staging: row, k-quarter (8 floats)
  int bc = t >> 1, bh = t & 1;   // B staging: col, k-half (16 shorts)

  int ksteps = (K + 31) >> 5;
  for (int s = 0; s < ksteps; ++s) {
    int k0 = s << 5;
    // ---- stage A (fp32 -> hi/lo bf16) ----
    float av[8];
    long ar = row0 + sr;
    if (ar < M && k0 + sq * 8 + 8 <= K) {
      const float4* p = (const float4*)&A[ar * K + k0 + sq * 8];
      float4 v0 = p[0], v1 = p[1];
      av[0] = v0.x; av[1] = v0.y; av[2] = v0.z; av[3] = v0.w;
      av[4] = v1.x; av[5] = v1.y; av[6] = v1.z; av[7] = v1.w;
    } else {
      #pragma unroll
      for (int i = 0; i < 8; ++i) {
        int k = k0 + sq * 8 + i;
        av[i] = (ar < M && k < K) ? A[ar * K + k] : 0.f;
      }
    }
    short8 hv, lv;
    #pragma unroll
    for (int i = 0; i < 8; ++i) {
      unsigned short h = f2bf(av[i]);
      hv[i] = (short)h;
      lv[i] = (short)f2bf(av[i] - bf2f(h));
    }
    *(short8*)&As_h[sr * 40 + sq * 8] = hv;
    *(short8*)&As_l[sr * 40 + sq * 8] = lv;
    // ---- stage B (precomputed bf16, transposed) ----
    {
      const short8* ph = (const short8*)&Wh[(bc << 10) + k0 + bh * 16];
      const short8* pl = (const short8*)&Wl[(bc << 10) + k0 + bh * 16];
      short8* dh = (short8*)&Bs_h[bc * 40 + bh * 16];
      short8* dl = (short8*)&Bs_l[bc * 40 + bh * 16];
      dh[0] = ph[0]; dh[1] = ph[1];
      dl[0] = pl[0]; dl[1] = pl[1];
    }
    __syncthreads();
    // ---- compute ----
    short8 ah[4], alo[4];
    #pragma unroll
    for (int m = 0; m < 4; ++m) {
      int off = (m * 16 + (lane & 15)) * 40 + (lane >> 4) * 8;
      ah[m]  = *(const short8*)&As_h[off];
      alo[m] = *(const short8*)&As_l[off];
    }
    #pragma unroll
    for (int n = 0; n < 2; ++n) {
      int off = (w * 32 + n * 16 + (lane & 15)) * 40 + (lane >> 4) * 8;
      short8 bh8 = *(const short8*)&Bs_h[off];
      short8 bl8 = *(const short8*)&Bs_l[off];
      #pragma unroll
      for (int m = 0; m < 4; ++m) {
        acc[m][n] = __builtin_amdgcn_mfma_f32_16x16x32_bf16(ah[m], bh8, acc[m][n], 0, 0, 0);
        acc[m][n] = __builtin_amdgcn_mfma_f32_16x16x32_bf16(alo[m], bh8, acc[m][n], 0, 0, 0);
        acc[m][n] = __builtin_amdgcn_mfma_f32_16x16x32_bf16(ah[m], bl8, acc[m][n], 0, 0, 0);
      }
    }
    __syncthreads();
  }
  // ---- epilogue: C/D layout col=lane&15, row=(lane>>4)*4+i ----
  int cc = lane & 15, cq = lane >> 4;
  #pragma unroll
  for (int m = 0; m < 4; ++m) {
    #pragma unroll
    for (int i = 0; i < 4; ++i) {
      long row = row0 + m * 16 + cq * 4 + i;
      if (row < M) {
        #pragma unroll
        for (int n = 0; n < 2; ++n)
          out[row * 128 + w * 32 + n * 16 + cc] = acc[m][n][i];
      }
    }
  }
}

// ---------------- small fp32 GEMM for layer 2 (N=16) ----------------

template<int NC>
__global__ void k_gemm(const float* __restrict__ A, const float* __restrict__ W,
                       float* __restrict__ out, int M, int K) {
  constexpr int TR = 32;
  constexpr int RG = 256 / NC;
  constexpr int RPT = TR / RG;
  __shared__ float xs[TR][8];
  int t = threadIdx.x;
  int col = t % NC, rg = t / NC;
  long row0 = (long)blockIdx.x * TR;
  float acc[RPT];
  #pragma unroll
  for (int r = 0; r < RPT; ++r) acc[r] = 0.f;
  int lr = t >> 3, lc = t & 7;
  for (int k0 = 0; k0 < K; k0 += 8) {
    long grow = row0 + lr;
    xs[lr][lc] = (grow < M) ? A[grow * K + k0 + lc] : 0.f;
    __syncthreads();
    #pragma unroll
    for (int kk = 0; kk < 8; ++kk) {
      float w = W[(long)(k0 + kk) * NC + col];
      #pragma unroll
      for (int r = 0; r < RPT; ++r)
        acc[r] += xs[rg * RPT + r][kk] * w;
    }
    __syncthreads();
  }
  #pragma unroll
  for (int r = 0; r < RPT; ++r) {
    long row = row0 + rg * RPT + r;
    if (row < M) out[row * NC + col] = acc[r];
  }
}

// ---------------- attention coefficients ----------------

__global__ void k_al(const float* __restrict__ h, const float* __restrict__ a_s,
                     const float* __restrict__ a_d, float* __restrict__ als,
                     float* __restrict__ ald, int n, int H, int C) {
  int t = blockIdx.x * blockDim.x + threadIdx.x;
  if (t >= n * H) return;
  int hd = t % H;
  const float* hp = h + (long)t * C;
  float s1 = 0.f, s2 = 0.f;
  for (int c = 0; c < C; ++c) {
    float v = hp[c];
    s1 += v * a_s[hd * C + c];
    s2 += v * a_d[hd * C + c];
  }
  als[t] = s1; ald[t] = s2;
}

// ---------------- per-dst aggregation, H=8, C=16 (128 ch) ----------------

__global__ void k_agg128(const float* __restrict__ h, const float* __restrict__ als,
                         const float* __restrict__ ald, const int* __restrict__ ptr,
                         const int* __restrict__ srcs, const float* __restrict__ bias,
                         float* __restrict__ out, int n, int do_elu) {
  int wid = (int)(((long)blockIdx.x * blockDim.x + threadIdx.x) >> 6);
  if (wid >= n) return;
  int lane = threadIdx.x & 63;
  int p0 = ptr[wid], deg = ptr[wid + 1] - p0;
  int hA = lane & 7;
  float aldA = ald[wid * 8 + hA];
  float mx = -1e30f;
  for (int j = (lane >> 3); j < deg; j += 8) {
    float l = als[srcs[p0 + j] * 8 + hA] + aldA;
    l = l > 0.f ? l : 0.2f * l;
    mx = fmaxf(mx, l);
  }
  #pragma unroll
  for (int d = 8; d < 64; d <<= 1) mx = fmaxf(mx, __shfl_xor(mx, d));
  int hB = lane >> 3;
  float m = __shfl(mx, hB);
  float aldB = ald[wid * 8 + hB];
  int c0 = 2 * lane;
  float acc0 = 0.f, acc1 = 0.f, dsum = 0.f;
  for (int j = 0; j < deg; ++j) {
    int s = srcs[p0 + j];
    float l = als[s * 8 + hB] + aldB;
    l = l > 0.f ? l : 0.2f * l;
    float e = __expf(l - m);
    dsum += e;
    const float2 hv = *(const float2*)(h + (long)s * 128 + c0);
    acc0 += e * hv.x;
    acc1 += e * hv.y;
  }
  float inv = 1.f / (dsum + 1e-16f);
  float o0 = acc0 * inv + bias[c0];
  float o1 = acc1 * inv + bias[c0 + 1];
  if (do_elu) {
    o0 = o0 > 0.f ? o0 : (__expf(o0) - 1.f);
    o1 = o1 > 0.f ? o1 : (__expf(o1) - 1.f);
  }
  *(float2*)(out + (long)wid * 128 + c0) = make_float2(o0, o1);
}

// ---------------- per-dst aggregation, H=1, C=16 ----------------

__global__ void k_agg16(const float* __restrict__ h, const float* __restrict__ als,
                        const float* __restrict__ ald, const int* __restrict__ ptr,
                        const int* __restrict__ srcs, const float* __restrict__ bias,
                        float* __restrict__ out, int n) {
  int wid = (int)(((long)blockIdx.x * blockDim.x + threadIdx.x) >> 6);
  if (wid >= n) return;
  int lane = threadIdx.x & 63;
  int p0 = ptr[wid], deg = ptr[wid + 1] - p0;
  float aldv = ald[wid];
  float mx = -1e30f;
  for (int j = lane; j < deg; j += 64) {
    float l = als[srcs[p0 + j]] + aldv;
    l = l > 0.f ? l : 0.2f * l;
    mx = fmaxf(mx, l);
  }
  #pragma unroll
  for (int d = 1; d < 64; d <<= 1) mx = fmaxf(mx, __shfl_xor(mx, d));
  int g = lane >> 4, c = lane & 15;
  float acc = 0.f, dsum = 0.f;
  for (int j = g; j < deg; j += 4) {
    int s = srcs[p0 + j];
    float l = als[s] + aldv;
    l = l > 0.f ? l : 0.2f * l;
    float e = __expf(l - mx);
    dsum += e;
    acc += e * h[(long)s * 16 + c];
  }
  #pragma unroll
  for (int d = 16; d < 64; d <<= 1) {
    acc += __shfl_xor(acc, d);
    dsum += __shfl_xor(dsum, d);
  }
  if (lane < 16)
    out[(long)wid * 16 + lane] = acc / (dsum + 1e-16f) + bias[lane];
}

// ---------------- launch ----------------

extern "C" void kernel_launch(void* const* d_in, const int* in_sizes, int n_in,
                              void* d_out, int out_size, void* d_ws, size_t ws_size,
                              hipStream_t stream) {
  const float* x  = (const float*)d_in[0];
  const int*   ei = (const int*)d_in[1];
  const float* W0 = (const float*)d_in[2];
  const float* as0= (const float*)d_in[3];
  const float* ad0= (const float*)d_in[4];
  const float* b0 = (const float*)d_in[5];
  const float* W1 = (const float*)d_in[6];
  const float* as1= (const float*)d_in[7];
  const float* ad1= (const float*)d_in[8];
  const float* b1 = (const float*)d_in[9];
  const float* W2 = (const float*)d_in[10];
  const float* as2= (const float*)d_in[11];
  const float* ad2= (const float*)d_in[12];
  const float* b2 = (const float*)d_in[13];
  float* out = (float*)d_out;

  int E = in_sizes[1] / 2;
  int n = in_sizes[0] / GENES;

  char* ws = (char*)d_ws;
  size_t off = 0;
  auto alloc = [&](size_t bytes) {
    void* p = ws + off;
    off = (off + bytes + 255) & ~(size_t)255;
    return p;
  };
  int* ptr   = (int*)alloc((size_t)(n + 1) * sizeof(int));
  int* cur   = (int*)alloc((size_t)n * sizeof(int));
  int* srcs  = (int*)alloc((size_t)E * sizeof(int));
  float* A   = (float*)alloc((size_t)n * 128 * sizeof(float));
  float* B   = (float*)alloc((size_t)n * 128 * sizeof(float));
  float* als = (float*)alloc((size_t)n * 8 * sizeof(float));
  float* ald = (float*)alloc((size_t)n * 8 * sizeof(float));
  unsigned short* Wh = (unsigned short*)alloc((size_t)128 * 1024 * sizeof(unsigned short));
  unsigned short* Wl = (unsigned short*)alloc((size_t)128 * 1024 * sizeof(unsigned short));

  int eb = (E + 255) / 256;
  hipMemsetAsync(cur, 0, (size_t)n * sizeof(int), stream);
  k_deg<<<eb, 256, 0, stream>>>(ei, cur, E);
  k_scan<<<1, 1024, 0, stream>>>(cur, ptr, n);
  hipMemsetAsync(cur, 0, (size_t)n * sizeof(int), stream);
  k_scatter<<<eb, 256, 0, stream>>>(ei, ptr, cur, srcs, E);

  int mgb  = (n + 63) / 64;
  int gb   = (n + 31) / 32;
  int aggb = (int)(((long)n * 64 + 255) / 256);
  int alb  = (n * 8 + 255) / 256;
  int alb1 = (n + 255) / 256;
  int wsb  = (128 * 1024) / 256;

  // layer 0: x @ W0 -> A, attention, aggregate -> B (ELU)
  k_wsplit<<<wsb, 256, 0, stream>>>(W0, Wh, Wl, GENES);
  k_mgemm<<<mgb, 256, 0, stream>>>(x, Wh, Wl, A, n, GENES);
  k_al<<<alb, 256, 0, stream>>>(A, as0, ad0, als, ald, n, 8, 16);
  k_agg128<<<aggb, 256, 0, stream>>>(A, als, ald, ptr, srcs, b0, B, n, 1);

  // layer 1: B @ W1 -> A, aggregate -> B (ELU)
  k_wsplit<<<wsb, 256, 0, stream>>>(W1, Wh, Wl, 128);
  k_mgemm<<<mgb, 256, 0, stream>>>(B, Wh, Wl, A, n, 128);
  k_al<<<alb, 256, 0, stream>>>(A, as1, ad1, als, ald, n, 8, 16);
  k_agg128<<<aggb, 256, 0, stream>>>(A, als, ald, ptr, srcs, b1, B, n, 1);

  // layer 2: B @ W2 -> A[n*16], aggregate -> out (no ELU)
  k_gemm<16><<<gb, 256, 0, stream>>>(B, W2, A, n, 128);
  k_al<<<alb1, 256, 0, stream>>>(A, as2, ad2, als, ald, n, 1, 16);
  k_agg16<<<aggb, 256, 0, stream>>>(A, als, ald, ptr, srcs, b2, out, n);
}